// Round 11
// baseline (9738.918 us; speedup 1.0000x reference)
//
#include <hip/hip_runtime.h>
#include <hip/hip_bf16.h>

#define B_  32
#define T_  512
#define I_  512
#define H_  1024
#define O_  360
#define H3_ 3072
#define M_  (B_*T_)      // 16384

static constexpr int GRU_NB = 64;   // scan blocks (16 units each)

typedef __bf16 bf16x8 __attribute__((ext_vector_type(8)));
typedef float  f32x4  __attribute__((ext_vector_type(4)));

__device__ __forceinline__ float sigmoidf_(float x) {
  return 1.0f / (1.0f + __expf(-x));
}

__device__ __forceinline__ float ld_f32(const float* p) { return *p; }
__device__ __forceinline__ float ld_f32(const __hip_bfloat16* p) { return __bfloat162float(*p); }
__device__ __forceinline__ void st_f32(float* p, float v) { *p = v; }
__device__ __forceinline__ void st_f32(__hip_bfloat16* p, float v) { *p = __float2bfloat16(v); }

__device__ __forceinline__ unsigned short bf16_bits(float f) {
  __hip_bfloat16 b = __float2bfloat16(f);
  return *reinterpret_cast<unsigned short*>(&b);
}

// ---------------------------------------------------------------- utilities
__global__ void f32_to_bf16_k(const float* __restrict__ in,
                              __hip_bfloat16* __restrict__ out, int n) {
  int i = blockIdx.x * blockDim.x + threadIdx.x;
  int stride = gridDim.x * blockDim.x;
  for (; i < n; i += stride) out[i] = __float2bfloat16(in[i]);
}

__global__ void gru_init_k(__hip_bfloat16* __restrict__ hbuf,
                           unsigned* __restrict__ tags) {
  const int tid0  = blockIdx.x * blockDim.x + threadIdx.x;
  const int stride = gridDim.x * blockDim.x;
  for (int i = tid0; i < 2 * B_ * H_; i += stride) hbuf[i] = __float2bfloat16(0.0f);
  if (tid0 < 256) tags[tid0] = 0u;   // [0..127] wave tags
}

// ---------------------------------------------------------------- clock probe
// Fixed-work dependent-FMA spin: 4 chains, `iters` rounds, ~8 cy/round.
// dur_us of this dispatch directly measures sclk: 1.2 Mcy total.
__global__ __launch_bounds__(256)
void clock_probe_k(int iters) {
  float d0 = 1.0f + threadIdx.x * 1e-7f;
  float d1 = 1.1f, d2 = 1.2f, d3 = 1.3f;
  for (int i = 0; i < iters; ++i) {
    d0 = fmaf(d0, 0.99999994f, 1e-9f);
    d1 = fmaf(d1, 0.99999994f, 1e-9f);
    d2 = fmaf(d2, 0.99999994f, 1e-9f);
    d3 = fmaf(d3, 0.99999994f, 1e-9f);
  }
  asm volatile("" :: "v"(d0), "v"(d1), "v"(d2), "v"(d3));
}

// ---------------------------------------------------------------- MFMA GEMM
// C[M,N] = act(A[M,K] fp32 * W[N,K]^T fp32 + bias[N]) via split-bf16:
// a = ah + al (ah=bf16(a), al=bf16(a-ah)); D = Ah·Wh + Ah·Wl + Al·Wh.
// 128x128 tile, BK=32, 4 waves (2x2 of 64x64), 16x16x32 MFMA.
// Frag layout (verified in gru_scan): A-op lane reads A[l&15][(l>>4)*8+0..7];
// B-op lane reads W[l&15][(l>>4)*8+0..7]; D: row=(l>>4)*4+reg, col=l&15.
// M mult of 128; K mult of 32; N arbitrary (guarded).
template <int ACT, typename OT>
__global__ __launch_bounds__(256)
void mgemm_bt(const float* __restrict__ A, const float* __restrict__ W,
              const float* __restrict__ bias, OT* __restrict__ C,
              int M, int N, int K, int lda) {
  __shared__ __hip_bfloat16 Ah[128][40], Al[128][40];   // pad 32->40: no conflicts
  __shared__ __hip_bfloat16 Wh[128][40], Wl[128][40];
  const int tid  = threadIdx.x;
  const int lane = tid & 63;
  const int wv   = tid >> 6;
  const int bm   = blockIdx.y * 128;
  const int bn   = blockIdx.x * 128;
  const int msub = (wv & 1) * 64;
  const int nsub = (wv >> 1) * 64;
  const int fr   = lane & 15;     // frag row(col) selector
  const int fk   = lane >> 4;     // k-octet

  f32x4 acc[4][4];
#pragma unroll
  for (int i = 0; i < 4; ++i)
#pragma unroll
    for (int j = 0; j < 4; ++j) acc[i][j] = (f32x4){0.f, 0.f, 0.f, 0.f};

  const int sr = tid >> 1;          // staging row 0..127
  const int sc = (tid & 1) * 16;    // staging col base (0/16)
  const float* Ap = A + (size_t)(bm + sr) * lda + sc;
  const bool wok = (bn + sr) < N;
  const float* Wp = W + (size_t)(wok ? (bn + sr) : 0) * K + sc;

  for (int k0 = 0; k0 < K; k0 += 32) {
    float av[16], wvv[16];
#pragma unroll
    for (int j = 0; j < 4; ++j) {
      float4 t = *(const float4*)(Ap + k0 + j * 4);
      av[j*4+0] = t.x; av[j*4+1] = t.y; av[j*4+2] = t.z; av[j*4+3] = t.w;
      float4 u = wok ? *(const float4*)(Wp + k0 + j * 4)
                     : make_float4(0.f, 0.f, 0.f, 0.f);
      wvv[j*4+0] = u.x; wvv[j*4+1] = u.y; wvv[j*4+2] = u.z; wvv[j*4+3] = u.w;
    }
    __syncthreads();   // previous tile fully consumed
#pragma unroll
    for (int e = 0; e < 16; ++e) {
      __hip_bfloat16 h = __float2bfloat16(av[e]);
      Ah[sr][sc + e] = h;
      Al[sr][sc + e] = __float2bfloat16(av[e] - __bfloat162float(h));
      __hip_bfloat16 g = __float2bfloat16(wvv[e]);
      Wh[sr][sc + e] = g;
      Wl[sr][sc + e] = __float2bfloat16(wvv[e] - __bfloat162float(g));
    }
    __syncthreads();

    bf16x8 ah[4], al[4];
#pragma unroll
    for (int mf = 0; mf < 4; ++mf) {
      ah[mf] = *(const bf16x8*)&Ah[msub + mf * 16 + fr][fk * 8];
      al[mf] = *(const bf16x8*)&Al[msub + mf * 16 + fr][fk * 8];
    }
#pragma unroll
    for (int nf = 0; nf < 4; ++nf) {
      bf16x8 bh = *(const bf16x8*)&Wh[nsub + nf * 16 + fr][fk * 8];
      bf16x8 bl = *(const bf16x8*)&Wl[nsub + nf * 16 + fr][fk * 8];
#pragma unroll
      for (int mf = 0; mf < 4; ++mf) {
        acc[mf][nf] = __builtin_amdgcn_mfma_f32_16x16x32_bf16(ah[mf], bh, acc[mf][nf], 0, 0, 0);
        acc[mf][nf] = __builtin_amdgcn_mfma_f32_16x16x32_bf16(ah[mf], bl, acc[mf][nf], 0, 0, 0);
        acc[mf][nf] = __builtin_amdgcn_mfma_f32_16x16x32_bf16(al[mf], bh, acc[mf][nf], 0, 0, 0);
      }
    }
  }

#pragma unroll
  for (int nf = 0; nf < 4; ++nf) {
    const int n = bn + nsub + nf * 16 + fr;
    if (n < N) {
      const float bj = bias[n];
#pragma unroll
      for (int mf = 0; mf < 4; ++mf)
#pragma unroll
        for (int r = 0; r < 4; ++r) {
          const int m = bm + msub + mf * 16 + fk * 4 + r;
          float v = acc[mf][nf][r] + bj;
          if (ACT) v = fmaxf(v, 0.0f);
          st_f32(&C[(size_t)m * N + n], v);
        }
    }
  }
}

// ---------------------------------------------------------------- GRU scan
// R6/R10 structure: 64 blocks x 128 threads (2 waves). Block owns 16 hidden
// units; wave bt owns batch rows bt*16..+15 (full K=1024). Data-flow tags
// through L3 (sc1 relaxed), no RMW, no __syncthreads. Tags genuinely zeroed
// by gru_init_k (R10 fix) and visible via the init kernel's end-of-dispatch
// release flush.
// NOTE: xg and hs may ALIAS (fp32 path interleaves hs into xg's r columns).
template <typename XT>
__global__ __launch_bounds__(128)
void gru_scan(const XT* xg,                            // [B,T,3H]
              const __hip_bfloat16* __restrict__ Wbf,  // [3H][H] bf16
              const float* __restrict__ bhh,           // [3H]
              float* hs, int hs_ld,                    // [B,T,*] out
              __hip_bfloat16* hbuf,                    // [2][B][H] bf16
              unsigned* tags) {                        // [64 blocks][2 waves]
  const int tid  = threadIdx.x;
  const int lane = tid & 63;
  const int bt   = tid >> 6;
  const int col  = lane & 15;
  const int krow = lane >> 4;
  const int u    = blockIdx.x * 16 + col;
  const int bb   = bt * 16 + krow * 4;

  const float bhr = bhh[u];
  const float bhz = bhh[H_ + u];
  const float bhn = bhh[2 * H_ + u];

  const bf16x8* Wv = (const bf16x8*)Wbf;
  const bf16x8* wr = Wv + (size_t)u * 128 + krow;
  const bf16x8* wz = wr + (size_t)H_ * 128;
  const bf16x8* wn = wz + (size_t)H_ * 128;

  const unsigned* mytag = tags + ((lane << 1) | bt);
  unsigned* ourtag = tags + ((blockIdx.x << 1) | bt);

  f32x4 hold = {0.f, 0.f, 0.f, 0.f};

  float pxr[4], pxz[4], pxn[4];
#pragma unroll
  for (int c = 0; c < 4; ++c) {
    const XT* xp = xg + ((size_t)(bb + c) * T_ + 0) * H3_;
    pxr[c] = ld_f32(xp + u);
    pxz[c] = ld_f32(xp + H_ + u);
    pxn[c] = ld_f32(xp + 2 * H_ + u);
  }

  for (int t = 0; t < T_; ++t) {
    const int cur = t & 1;

    if (t > 0) {
      unsigned tg;
      do {
        tg = __hip_atomic_load(mytag, __ATOMIC_RELAXED, __HIP_MEMORY_SCOPE_AGENT);
      } while (__any(tg < (unsigned)t));
      __builtin_amdgcn_sched_barrier(0);
    }

    const unsigned long long* ab =
        (const unsigned long long*)(hbuf + cur * (B_ * H_)) +
        (size_t)(bt * 16 + col) * 256 + krow * 2;

    f32x4 ar = {0.f, 0.f, 0.f, 0.f};
    f32x4 az = {0.f, 0.f, 0.f, 0.f};
    f32x4 an = {0.f, 0.f, 0.f, 0.f};
#pragma unroll 8
    for (int ks = 0; ks < 32; ++ks) {
      union { unsigned long long q[2]; bf16x8 v; } A;
      A.q[0] = __hip_atomic_load(ab + ks * 8 + 0, __ATOMIC_RELAXED, __HIP_MEMORY_SCOPE_AGENT);
      A.q[1] = __hip_atomic_load(ab + ks * 8 + 1, __ATOMIC_RELAXED, __HIP_MEMORY_SCOPE_AGENT);
      ar = __builtin_amdgcn_mfma_f32_16x16x32_bf16(A.v, wr[ks * 4], ar, 0, 0, 0);
      az = __builtin_amdgcn_mfma_f32_16x16x32_bf16(A.v, wz[ks * 4], az, 0, 0, 0);
      an = __builtin_amdgcn_mfma_f32_16x16x32_bf16(A.v, wn[ks * 4], an, 0, 0, 0);
    }

    float hv[4];
#pragma unroll
    for (int c = 0; c < 4; ++c) {
      const float r = sigmoidf_(pxr[c] + ar[c] + bhr);
      const float z = sigmoidf_(pxz[c] + az[c] + bhz);
      const float n = tanhf(pxn[c] + r * (an[c] + bhn));
      const float h = (1.0f - z) * n + z * hold[c];
      hold[c] = h;
      hv[c] = h;
    }

    unsigned* hn32 = (unsigned*)(hbuf + (cur ^ 1) * (B_ * H_));
    const int ue2 = (u & ~1) >> 1;
    const int c0 = (lane & 1) ? 2 : 0;
#pragma unroll
    for (int c = 0; c < 4; ++c) {
      const float other = __shfl_xor(hv[c], 1, 64);
      unsigned p;
      if (lane & 1)
        p = (unsigned)bf16_bits(other) | ((unsigned)bf16_bits(hv[c]) << 16);
      else
        p = (unsigned)bf16_bits(hv[c]) | ((unsigned)bf16_bits(other) << 16);
      if (c == c0 || c == c0 + 1)
        __hip_atomic_store(hn32 + (size_t)(bb + c) * 512 + ue2, p,
                           __ATOMIC_RELAXED, __HIP_MEMORY_SCOPE_AGENT);
    }

    asm volatile("s_waitcnt vmcnt(0)" ::: "memory");
    if (lane == 0)
      __hip_atomic_store(ourtag, (unsigned)(t + 1),
                         __ATOMIC_RELAXED, __HIP_MEMORY_SCOPE_AGENT);

#pragma unroll
    for (int c = 0; c < 4; ++c)
      hs[((size_t)(bb + c) * T_ + t) * hs_ld + u] = hv[c];

    if (t + 1 < T_) {
#pragma unroll
      for (int c = 0; c < 4; ++c) {
        const XT* xp = xg + ((size_t)(bb + c) * T_ + (t + 1)) * H3_;
        pxr[c] = ld_f32(xp + u);
        pxz[c] = ld_f32(xp + H_ + u);
        pxn[c] = ld_f32(xp + 2 * H_ + u);
      }
    }
  }
}

// ---------------------------------------------------------------- launch
extern "C" void kernel_launch(void* const* d_in, const int* in_sizes, int n_in,
                              void* d_out, int out_size, void* d_ws, size_t ws_size,
                              hipStream_t stream) {
  const float* x    = (const float*)d_in[0];
  const float* W1   = (const float*)d_in[1];
  const float* b1   = (const float*)d_in[2];
  const float* W2   = (const float*)d_in[3];
  const float* b2   = (const float*)d_in[4];
  const float* Wih  = (const float*)d_in[5];
  const float* bih  = (const float*)d_in[6];
  const float* Whh  = (const float*)d_in[7];
  const float* bhh  = (const float*)d_in[8];
  const float* Wout = (const float*)d_in[9];
  const float* bout = (const float*)d_in[10];
  float* out = (float*)d_out;

  const size_t MB = (size_t)1 << 20;
  char* ws = (char*)d_ws;

  if (ws_size >= 256 * MB) {
    // ---------------- fp32-xg path (256 MiB) ----------------
    float* h2 = (float*)ws;
    float* h1 = (float*)(ws + 64 * MB);
    float* xg = (float*)(ws + 64 * MB);
    __hip_bfloat16* Wbf  = (__hip_bfloat16*)ws;
    __hip_bfloat16* hbuf = (__hip_bfloat16*)(ws + 8 * MB);
    unsigned* tags = (unsigned*)(ws + 9 * MB);
    float* hs = xg;  const int hs_ld = H3_;

    mgemm_bt<1, float><<<dim3(8, 128), 256, 0, stream>>>(x, W1, b1, h1, M_, H_, I_, I_);
    mgemm_bt<1, float><<<dim3(8, 128), 256, 0, stream>>>(h1, W2, b2, h2, M_, H_, H_, H_);
    mgemm_bt<0, float><<<dim3(24, 128), 256, 0, stream>>>(h2, Wih, bih, xg, M_, H3_, H_, H_);
    f32_to_bf16_k<<<768, 256, 0, stream>>>(Whh, Wbf, H3_ * H_);
    gru_init_k<<<32, 256, 0, stream>>>(hbuf, tags);
    gru_scan<float><<<GRU_NB, 128, 0, stream>>>(xg, Wbf, bhh, hs, hs_ld, hbuf, tags);
    clock_probe_k<<<192, 256, 0, stream>>>(150000);
    mgemm_bt<0, float><<<dim3(3, 128), 256, 0, stream>>>(hs, Wout, bout, out, M_, O_, H_, hs_ld);
  } else if (ws_size >= 167 * MB) {
    // ---------------- bf16-xg fallback (167 MiB) ----------------
    float* h2 = (float*)ws;
    float* hs = (float*)ws;
    float* h1 = (float*)(ws + 64 * MB);
    __hip_bfloat16* xg   = (__hip_bfloat16*)(ws + 64 * MB);
    __hip_bfloat16* Wbf  = (__hip_bfloat16*)(ws + 160 * MB);
    __hip_bfloat16* hbuf = (__hip_bfloat16*)(ws + 166 * MB);
    unsigned* tags = (unsigned*)(ws + 166 * MB + 256 * 1024);

    mgemm_bt<1, float><<<dim3(8, 128), 256, 0, stream>>>(x, W1, b1, h1, M_, H_, I_, I_);
    mgemm_bt<1, float><<<dim3(8, 128), 256, 0, stream>>>(h1, W2, b2, h2, M_, H_, H_, H_);
    mgemm_bt<0, __hip_bfloat16><<<dim3(24, 128), 256, 0, stream>>>(h2, Wih, bih, xg, M_, H3_, H_, H_);
    f32_to_bf16_k<<<768, 256, 0, stream>>>(Whh, Wbf, H3_ * H_);
    gru_init_k<<<32, 256, 0, stream>>>(hbuf, tags);
    gru_scan<__hip_bfloat16><<<GRU_NB, 128, 0, stream>>>(xg, Wbf, bhh, hs, H_, hbuf, tags);
    clock_probe_k<<<192, 256, 0, stream>>>(150000);
    mgemm_bt<0, float><<<dim3(3, 128), 256, 0, stream>>>(hs, Wout, bout, out, M_, O_, H_, H_);
  }
  // else: insufficient workspace -> zeros (visible failure)
}

// Round 13
// 7371.133 us; speedup vs baseline: 1.3212x; 1.3212x over previous
//
#include <hip/hip_runtime.h>
#include <hip/hip_bf16.h>

#define B_  32
#define T_  512
#define I_  512
#define H_  1024
#define O_  360
#define H3_ 3072
#define M_  (B_*T_)      // 16384

static constexpr int GRU_NB = 64;   // scan blocks (16 units each)

typedef __bf16 bf16x8 __attribute__((ext_vector_type(8)));
typedef float  f32x4  __attribute__((ext_vector_type(4)));

__device__ __forceinline__ float sigmoidf_(float x) {
  return 1.0f / (1.0f + __expf(-x));
}
__device__ __forceinline__ float ld_f32(const float* p) { return *p; }
__device__ __forceinline__ float ld_f32(const __hip_bfloat16* p) { return __bfloat162float(*p); }
__device__ __forceinline__ void st_f32(float* p, float v) { *p = v; }
__device__ __forceinline__ void st_f32(__hip_bfloat16* p, float v) { *p = __float2bfloat16(v); }
__device__ __forceinline__ unsigned short bf16_bits(float f) {
  __hip_bfloat16 b = __float2bfloat16(f);
  return *reinterpret_cast<unsigned short*>(&b);
}
__device__ __forceinline__ unsigned short bits_of(__hip_bfloat16 b) {
  return *reinterpret_cast<unsigned short*>(&b);
}

// ---------------------------------------------------------------- utilities
__global__ void f32_to_bf16_k(const float* __restrict__ in,
                              __hip_bfloat16* __restrict__ out, int n) {
  int i = blockIdx.x * blockDim.x + threadIdx.x;
  int stride = gridDim.x * blockDim.x;
  for (; i < n; i += stride) out[i] = __float2bfloat16(in[i]);
}

// (R10 fix retained: separate loop index; tag words genuinely written.)
__global__ void gru_init_k(__hip_bfloat16* __restrict__ hbuf,
                           unsigned* __restrict__ tags) {
  const int tid0  = blockIdx.x * blockDim.x + threadIdx.x;
  const int stride = gridDim.x * blockDim.x;
  for (int i = tid0; i < 2 * B_ * H_; i += stride) hbuf[i] = __float2bfloat16(0.0f);
  if (tid0 < 256) tags[tid0] = 0u;
}

// ---------------------------------------------------------------- MFMA GEMM
// C[M,N] = act(A[M,K] fp32 * W[N,K]^T fp32 + bias[N]) via split-bf16:
// a = ah + al; D = Ah*Wh + Ah*Wl + Al*Wh  (fp32-class accuracy).
// 128x128 tile, BK=32, 4 waves (2x2 of 64x64), 16x16x32 MFMA.
// v2: conversions in registers, packed ds_write_b128 staging (8 stores/thread
// /tile instead of 64 scalar b16 stores). Row stride 40 elems = 80 B (16B-
// aligned); read pattern identical to the R11-verified kernel.
template <int ACT, typename OT>
__global__ __launch_bounds__(256)
void mgemm_bt(const float* __restrict__ A, const float* __restrict__ W,
              const float* __restrict__ bias, OT* __restrict__ C,
              int M, int N, int K, int lda) {
  __shared__ __hip_bfloat16 Ah[128][40], Al[128][40];
  __shared__ __hip_bfloat16 Wh[128][40], Wl[128][40];
  const int tid  = threadIdx.x;
  const int lane = tid & 63;
  const int wv   = tid >> 6;
  const int bm   = blockIdx.y * 128;
  const int bn   = blockIdx.x * 128;
  const int msub = (wv & 1) * 64;
  const int nsub = (wv >> 1) * 64;
  const int fr   = lane & 15;
  const int fk   = lane >> 4;

  f32x4 acc[4][4];
#pragma unroll
  for (int i = 0; i < 4; ++i)
#pragma unroll
    for (int j = 0; j < 4; ++j) acc[i][j] = (f32x4){0.f, 0.f, 0.f, 0.f};

  const int sr = tid >> 1;          // staging row 0..127
  const int sc = (tid & 1) * 16;    // staging col base (0/16)
  const float* Ap = A + (size_t)(bm + sr) * lda + sc;
  const bool wok = (bn + sr) < N;
  const float* Wp = W + (size_t)(wok ? (bn + sr) : 0) * K + sc;

  for (int k0 = 0; k0 < K; k0 += 32) {
    float av[16], wvv[16];
#pragma unroll
    for (int j = 0; j < 4; ++j) {
      float4 t = *(const float4*)(Ap + k0 + j * 4);
      av[j*4+0] = t.x; av[j*4+1] = t.y; av[j*4+2] = t.z; av[j*4+3] = t.w;
      float4 u = wok ? *(const float4*)(Wp + k0 + j * 4)
                     : make_float4(0.f, 0.f, 0.f, 0.f);
      wvv[j*4+0] = u.x; wvv[j*4+1] = u.y; wvv[j*4+2] = u.z; wvv[j*4+3] = u.w;
    }

    // in-register hi/lo split + pack (2 bf16 per u32)
    unsigned pah[8], pal[8], pwh[8], pwl[8];
#pragma unroll
    for (int e = 0; e < 8; ++e) {
      __hip_bfloat16 a0 = __float2bfloat16(av[2*e]);
      __hip_bfloat16 a1 = __float2bfloat16(av[2*e+1]);
      pah[e] = (unsigned)bits_of(a0) | ((unsigned)bits_of(a1) << 16);
      pal[e] = (unsigned)bf16_bits(av[2*e]   - __bfloat162float(a0)) |
               ((unsigned)bf16_bits(av[2*e+1] - __bfloat162float(a1)) << 16);
      __hip_bfloat16 w0 = __float2bfloat16(wvv[2*e]);
      __hip_bfloat16 w1 = __float2bfloat16(wvv[2*e+1]);
      pwh[e] = (unsigned)bits_of(w0) | ((unsigned)bits_of(w1) << 16);
      pwl[e] = (unsigned)bf16_bits(wvv[2*e]   - __bfloat162float(w0)) |
               ((unsigned)bf16_bits(wvv[2*e+1] - __bfloat162float(w1)) << 16);
    }

    __syncthreads();   // previous tile fully consumed
    *(uint4*)&Ah[sr][sc]     = make_uint4(pah[0], pah[1], pah[2], pah[3]);
    *(uint4*)&Ah[sr][sc + 8] = make_uint4(pah[4], pah[5], pah[6], pah[7]);
    *(uint4*)&Al[sr][sc]     = make_uint4(pal[0], pal[1], pal[2], pal[3]);
    *(uint4*)&Al[sr][sc + 8] = make_uint4(pal[4], pal[5], pal[6], pal[7]);
    *(uint4*)&Wh[sr][sc]     = make_uint4(pwh[0], pwh[1], pwh[2], pwh[3]);
    *(uint4*)&Wh[sr][sc + 8] = make_uint4(pwh[4], pwh[5], pwh[6], pwh[7]);
    *(uint4*)&Wl[sr][sc]     = make_uint4(pwl[0], pwl[1], pwl[2], pwl[3]);
    *(uint4*)&Wl[sr][sc + 8] = make_uint4(pwl[4], pwl[5], pwl[6], pwl[7]);
    __syncthreads();

    bf16x8 ah[4], al[4];
#pragma unroll
    for (int mf = 0; mf < 4; ++mf) {
      ah[mf] = *(const bf16x8*)&Ah[msub + mf * 16 + fr][fk * 8];
      al[mf] = *(const bf16x8*)&Al[msub + mf * 16 + fr][fk * 8];
    }
#pragma unroll
    for (int nf = 0; nf < 4; ++nf) {
      bf16x8 bh = *(const bf16x8*)&Wh[nsub + nf * 16 + fr][fk * 8];
      bf16x8 bl = *(const bf16x8*)&Wl[nsub + nf * 16 + fr][fk * 8];
#pragma unroll
      for (int mf = 0; mf < 4; ++mf) {
        acc[mf][nf] = __builtin_amdgcn_mfma_f32_16x16x32_bf16(ah[mf], bh, acc[mf][nf], 0, 0, 0);
        acc[mf][nf] = __builtin_amdgcn_mfma_f32_16x16x32_bf16(ah[mf], bl, acc[mf][nf], 0, 0, 0);
        acc[mf][nf] = __builtin_amdgcn_mfma_f32_16x16x32_bf16(al[mf], bh, acc[mf][nf], 0, 0, 0);
      }
    }
  }

#pragma unroll
  for (int nf = 0; nf < 4; ++nf) {
    const int n = bn + nsub + nf * 16 + fr;
    if (n < N) {
      const float bj = bias[n];
#pragma unroll
      for (int mf = 0; mf < 4; ++mf)
#pragma unroll
        for (int r = 0; r < 4; ++r) {
          const int m = bm + msub + mf * 16 + fk * 4 + r;
          float v = acc[mf][nf][r] + bj;
          if (ACT) v = fmaxf(v, 0.0f);
          st_f32(&C[(size_t)m * N + n], v);
        }
    }
  }
}

// ---------------------------------------------------------------- GRU scan
// Proven R6/R10 structure: 64 blocks x 128 threads (2 waves). Block owns 16
// hidden units; wave bt owns batch rows bt*16..+15 (full K=1024). Data-flow
// tags through L3 (sc1 relaxed), no RMW, no __syncthreads.
// NOTE: xg and hs may ALIAS (fp32 path interleaves hs into xg's r columns).
template <typename XT>
__global__ __launch_bounds__(128)
void gru_scan(const XT* xg,                            // [B,T,3H]
              const __hip_bfloat16* __restrict__ Wbf,  // [3H][H] bf16
              const float* __restrict__ bhh,           // [3H]
              float* hs, int hs_ld,                    // [B,T,*] out
              __hip_bfloat16* hbuf,                    // [2][B][H] bf16
              unsigned* tags) {                        // [64 blocks][2 waves]
  const int tid  = threadIdx.x;
  const int lane = tid & 63;
  const int bt   = tid >> 6;
  const int col  = lane & 15;
  const int krow = lane >> 4;
  const int u    = blockIdx.x * 16 + col;
  const int bb   = bt * 16 + krow * 4;

  const float bhr = bhh[u];
  const float bhz = bhh[H_ + u];
  const float bhn = bhh[2 * H_ + u];

  const bf16x8* Wv = (const bf16x8*)Wbf;
  const bf16x8* wr = Wv + (size_t)u * 128 + krow;
  const bf16x8* wz = wr + (size_t)H_ * 128;
  const bf16x8* wn = wz + (size_t)H_ * 128;

  const unsigned* mytag = tags + ((lane << 1) | bt);
  unsigned* ourtag = tags + ((blockIdx.x << 1) | bt);

  f32x4 hold = {0.f, 0.f, 0.f, 0.f};

  float pxr[4], pxz[4], pxn[4];
#pragma unroll
  for (int c = 0; c < 4; ++c) {
    const XT* xp = xg + ((size_t)(bb + c) * T_ + 0) * H3_;
    pxr[c] = ld_f32(xp + u);
    pxz[c] = ld_f32(xp + H_ + u);
    pxn[c] = ld_f32(xp + 2 * H_ + u);
  }

  for (int t = 0; t < T_; ++t) {
    const int cur = t & 1;

    if (t > 0) {
      unsigned tg;
      do {
        tg = __hip_atomic_load(mytag, __ATOMIC_RELAXED, __HIP_MEMORY_SCOPE_AGENT);
      } while (__any(tg < (unsigned)t));
      __builtin_amdgcn_sched_barrier(0);
    }

    const unsigned long long* ab =
        (const unsigned long long*)(hbuf + cur * (B_ * H_)) +
        (size_t)(bt * 16 + col) * 256 + krow * 2;

    f32x4 ar = {0.f, 0.f, 0.f, 0.f};
    f32x4 az = {0.f, 0.f, 0.f, 0.f};
    f32x4 an = {0.f, 0.f, 0.f, 0.f};
#pragma unroll 8
    for (int ks = 0; ks < 32; ++ks) {
      union { unsigned long long q[2]; bf16x8 v; } A;
      A.q[0] = __hip_atomic_load(ab + ks * 8 + 0, __ATOMIC_RELAXED, __HIP_MEMORY_SCOPE_AGENT);
      A.q[1] = __hip_atomic_load(ab + ks * 8 + 1, __ATOMIC_RELAXED, __HIP_MEMORY_SCOPE_AGENT);
      ar = __builtin_amdgcn_mfma_f32_16x16x32_bf16(A.v, wr[ks * 4], ar, 0, 0, 0);
      az = __builtin_amdgcn_mfma_f32_16x16x32_bf16(A.v, wz[ks * 4], az, 0, 0, 0);
      an = __builtin_amdgcn_mfma_f32_16x16x32_bf16(A.v, wn[ks * 4], an, 0, 0, 0);
    }

    float hv[4];
#pragma unroll
    for (int c = 0; c < 4; ++c) {
      const float r = sigmoidf_(pxr[c] + ar[c] + bhr);
      const float z = sigmoidf_(pxz[c] + az[c] + bhz);
      const float n = tanhf(pxn[c] + r * (an[c] + bhn));
      const float h = (1.0f - z) * n + z * hold[c];
      hold[c] = h;
      hv[c] = h;
    }

    unsigned* hn32 = (unsigned*)(hbuf + (cur ^ 1) * (B_ * H_));
    const int ue2 = (u & ~1) >> 1;
    const int c0 = (lane & 1) ? 2 : 0;
#pragma unroll
    for (int c = 0; c < 4; ++c) {
      const float other = __shfl_xor(hv[c], 1, 64);
      unsigned p;
      if (lane & 1)
        p = (unsigned)bf16_bits(other) | ((unsigned)bf16_bits(hv[c]) << 16);
      else
        p = (unsigned)bf16_bits(hv[c]) | ((unsigned)bf16_bits(other) << 16);
      if (c == c0 || c == c0 + 1)
        __hip_atomic_store(hn32 + (size_t)(bb + c) * 512 + ue2, p,
                           __ATOMIC_RELAXED, __HIP_MEMORY_SCOPE_AGENT);
    }

    asm volatile("s_waitcnt vmcnt(0)" ::: "memory");
    if (lane == 0)
      __hip_atomic_store(ourtag, (unsigned)(t + 1),
                         __ATOMIC_RELAXED, __HIP_MEMORY_SCOPE_AGENT);

#pragma unroll
    for (int c = 0; c < 4; ++c)
      hs[((size_t)(bb + c) * T_ + t) * hs_ld + u] = hv[c];

    if (t + 1 < T_) {
#pragma unroll
      for (int c = 0; c < 4; ++c) {
        const XT* xp = xg + ((size_t)(bb + c) * T_ + (t + 1)) * H3_;
        pxr[c] = ld_f32(xp + u);
        pxz[c] = ld_f32(xp + H_ + u);
        pxn[c] = ld_f32(xp + 2 * H_ + u);
      }
    }
  }
}

// ---------------------------------------------------------------- launch
extern "C" void kernel_launch(void* const* d_in, const int* in_sizes, int n_in,
                              void* d_out, int out_size, void* d_ws, size_t ws_size,
                              hipStream_t stream) {
  const float* x    = (const float*)d_in[0];
  const float* W1   = (const float*)d_in[1];
  const float* b1   = (const float*)d_in[2];
  const float* W2   = (const float*)d_in[3];
  const float* b2   = (const float*)d_in[4];
  const float* Wih  = (const float*)d_in[5];
  const float* bih  = (const float*)d_in[6];
  const float* Whh  = (const float*)d_in[7];
  const float* bhh  = (const float*)d_in[8];
  const float* Wout = (const float*)d_in[9];
  const float* bout = (const float*)d_in[10];
  float* out = (float*)d_out;

  const size_t MB = (size_t)1 << 20;
  char* ws = (char*)d_ws;

  if (ws_size >= 256 * MB) {
    // [0,64M): h2, later Wbf(6M)+hbuf(@8M)+tags(@9M)
    // [64,256M): xg fp32; h1 aliased at start; hs interleaved in r columns.
    float* h2 = (float*)ws;
    float* h1 = (float*)(ws + 64 * MB);
    float* xg = (float*)(ws + 64 * MB);
    __hip_bfloat16* Wbf  = (__hip_bfloat16*)ws;
    __hip_bfloat16* hbuf = (__hip_bfloat16*)(ws + 8 * MB);
    unsigned* tags = (unsigned*)(ws + 9 * MB);
    float* hs = xg;  const int hs_ld = H3_;

    mgemm_bt<1, float><<<dim3(8, 128), 256, 0, stream>>>(x, W1, b1, h1, M_, H_, I_, I_);
    mgemm_bt<1, float><<<dim3(8, 128), 256, 0, stream>>>(h1, W2, b2, h2, M_, H_, H_, H_);
    mgemm_bt<0, float><<<dim3(24, 128), 256, 0, stream>>>(h2, Wih, bih, xg, M_, H3_, H_, H_);
    f32_to_bf16_k<<<768, 256, 0, stream>>>(Whh, Wbf, H3_ * H_);
    gru_init_k<<<32, 256, 0, stream>>>(hbuf, tags);
    gru_scan<float><<<GRU_NB, 128, 0, stream>>>(xg, Wbf, bhh, hs, hs_ld, hbuf, tags);
    mgemm_bt<0, float><<<dim3(3, 128), 256, 0, stream>>>(hs, Wout, bout, out, M_, O_, H_, hs_ld);
  } else if (ws_size >= 167 * MB) {
    float* h2 = (float*)ws;
    float* hs = (float*)ws;
    float* h1 = (float*)(ws + 64 * MB);
    __hip_bfloat16* xg   = (__hip_bfloat16*)(ws + 64 * MB);
    __hip_bfloat16* Wbf  = (__hip_bfloat16*)(ws + 160 * MB);
    __hip_bfloat16* hbuf = (__hip_bfloat16*)(ws + 166 * MB);
    unsigned* tags = (unsigned*)(ws + 166 * MB + 256 * 1024);

    mgemm_bt<1, float><<<dim3(8, 128), 256, 0, stream>>>(x, W1, b1, h1, M_, H_, I_, I_);
    mgemm_bt<1, float><<<dim3(8, 128), 256, 0, stream>>>(h1, W2, b2, h2, M_, H_, H_, H_);
    mgemm_bt<0, __hip_bfloat16><<<dim3(24, 128), 256, 0, stream>>>(h2, Wih, bih, xg, M_, H3_, H_, H_);
    f32_to_bf16_k<<<768, 256, 0, stream>>>(Whh, Wbf, H3_ * H_);
    gru_init_k<<<32, 256, 0, stream>>>(hbuf, tags);
    gru_scan<__hip_bfloat16><<<GRU_NB, 128, 0, stream>>>(xg, Wbf, bhh, hs, H_, hbuf, tags);
    mgemm_bt<0, float><<<dim3(3, 128), 256, 0, stream>>>(hs, Wout, bout, out, M_, O_, H_, H_);
  }
  // else: insufficient workspace -> zeros (visible failure)
}